// Round 3
// baseline (272.422 us; speedup 1.0000x reference)
//
#include <hip/hip_runtime.h>
#include <hip/hip_bf16.h>

typedef _Float16 f16;
typedef _Float16 f16x8 __attribute__((ext_vector_type(8)));
typedef float f32x4 __attribute__((ext_vector_type(4)));

#define NB 8
#define NT 2048
#define NE 1024
#define NH 64

// ---------------- kernel 0: weight convert + transpose -------------------
// W [E][H] fp32  ->  WT [H][E] f16, three matrices in order q,k,v
__global__ void wconv_kernel(const float* __restrict__ Wk, const float* __restrict__ Wq,
                             const float* __restrict__ Wv, f16* __restrict__ wt) {
    int idx = blockIdx.x * 256 + threadIdx.x;
    if (idx >= 3 * NH * NE) return;
    int mat = idx >> 16;          // 65536 per matrix
    int o = idx & 65535;
    int h = o >> 10;              // 0..63
    int e = o & 1023;             // 0..1023
    const float* W = (mat == 0) ? Wq : (mat == 1) ? Wk : Wv;
    wt[idx] = (f16)W[e * NH + h];
}

// ---------------- kernel 1: fused QKV projection (MFMA f16) --------------
// x [16384][1024] fp32, wt [3][64][1024] f16
// outputs: Qh [B*T][64] f16, Kh [B*T][64] f16, VT [B][64][T] f16
__global__ __launch_bounds__(256) void qkv_proj_kernel(
        const float* __restrict__ x, const f16* __restrict__ wt,
        f16* __restrict__ Qh, f16* __restrict__ Kh, f16* __restrict__ VT) {
    const int wave = threadIdx.x >> 6;
    const int lane = threadIdx.x & 63;
    const int lr = lane & 15;   // row within 16-tile (A) / col (B,D)
    const int lg = lane >> 4;   // 0..3
    const int m0 = blockIdx.x * 128 + wave * 32;   // 32 rows per wave

    f32x4 acc[2][12] = {};   // 2 M-tiles x 12 N-tiles (q:0-3, k:4-7, v:8-11)

    for (int kk = 0; kk < NE; kk += 32) {
        f16x8 a[2];
#pragma unroll
        for (int mt = 0; mt < 2; ++mt) {
            const float* px = x + (size_t)(m0 + mt * 16 + lr) * NE + kk + lg * 8;
            float4 u0 = *(const float4*)px;
            float4 u1 = *(const float4*)(px + 4);
            f16x8 af = { (f16)u0.x, (f16)u0.y, (f16)u0.z, (f16)u0.w,
                         (f16)u1.x, (f16)u1.y, (f16)u1.z, (f16)u1.w };
            a[mt] = af;
        }
#pragma unroll
        for (int nt = 0; nt < 12; ++nt) {
            const f16* pw = wt + (size_t)(nt >> 2) * (NH * NE)
                               + (size_t)((nt & 3) * 16 + lr) * NE + kk + lg * 8;
            f16x8 b = *(const f16x8*)pw;
            acc[0][nt] = __builtin_amdgcn_mfma_f32_16x16x32_f16(a[0], b, acc[0][nt], 0, 0, 0);
            acc[1][nt] = __builtin_amdgcn_mfma_f32_16x16x32_f16(a[1], b, acc[1][nt], 0, 0, 0);
        }
    }

    // epilogue: D layout row=(lane>>4)*4+r, col=lane&15
#pragma unroll
    for (int mt = 0; mt < 2; ++mt) {
#pragma unroll
        for (int nt = 0; nt < 12; ++nt) {
            int mat = nt >> 2;
            int ncol = (nt & 3) * 16 + lr;
#pragma unroll
            for (int r = 0; r < 4; ++r) {
                int m = m0 + mt * 16 + lg * 4 + r;
                f16 val = (f16)acc[mt][nt][r];
                if (mat == 0) {
                    Qh[(size_t)m * NH + ncol] = val;
                } else if (mat == 1) {
                    Kh[(size_t)m * NH + ncol] = val;
                } else {
                    int bb = m >> 11;        // batch
                    int tt = m & 2047;       // time
                    VT[((size_t)bb * NH + ncol) * NT + tt] = val;
                }
            }
        }
    }
}

// ---------------- kernel 2: causal flash attention (MFMA f16) ------------
// Qh,Kh [B][T][64] f16; VT [B][64][T] f16; out [B][T][64] fp32
__global__ __launch_bounds__(256) void attn_kernel(
        const f16* __restrict__ Qh, const f16* __restrict__ Kh,
        const f16* __restrict__ VT, float* __restrict__ out) {
    __shared__ f16 pbuf[4][16][40];   // per-wave P tile [16 q][32 keys], padded 32->40

    const int wave = threadIdx.x >> 6;
    const int lane = threadIdx.x & 63;
    const int lr = lane & 15;
    const int lg = lane >> 4;

    const int b  = blockIdx.x >> 5;   // 32 q-blocks per batch
    const int qi = blockIdx.x & 31;
    const int qbase = qi * 64;
    const int qrow = qbase + wave * 16;   // this wave's 16 q-rows

    const f16* Qb = Qh + (size_t)b * NT * NH;
    const f16* Kb = Kh + (size_t)b * NT * NH;
    const f16* Vb = VT + (size_t)b * NH * NT;

    // Q fragments (2 halves of H=64)
    f16x8 qf[2];
#pragma unroll
    for (int h = 0; h < 2; ++h)
        qf[h] = *(const f16x8*)(Qb + (size_t)(qrow + lr) * NH + h * 32 + lg * 8);

    f32x4 o[4] = {};          // 4 h-tiles of 16
    float mrow[4], lrow[4];
#pragma unroll
    for (int r = 0; r < 4; ++r) { mrow[r] = -INFINITY; lrow[r] = 0.f; }

    const int nsteps = (qbase + 64) >> 5;   // KV steps of 32 keys
    const float scale = 0.125f;             // 1/sqrt(64)

    for (int s = 0; s < nsteps; ++s) {
        const int s0 = s * 32;

        // ---- QK^T: S[2] tiles of 16q x 16keys
        f32x4 S[2] = {};
#pragma unroll
        for (int t = 0; t < 2; ++t) {
#pragma unroll
            for (int h = 0; h < 2; ++h) {
                f16x8 kf = *(const f16x8*)(Kb + (size_t)(s0 + t * 16 + lr) * NH + h * 32 + lg * 8);
                S[t] = __builtin_amdgcn_mfma_f32_16x16x32_f16(qf[h], kf, S[t], 0, 0, 0);
            }
        }

        // ---- scale + causal mask (row q = qrow+lg*4+r, col key = s0+t*16+lr)
#pragma unroll
        for (int t = 0; t < 2; ++t) {
#pragma unroll
            for (int r = 0; r < 4; ++r) {
                int q = qrow + lg * 4 + r;
                int key = s0 + t * 16 + lr;
                float sv = S[t][r] * scale;
                S[t][r] = (key <= q) ? sv : -INFINITY;
            }
        }

        // ---- row max across the 16 lanes of each row group
        float mx[4];
#pragma unroll
        for (int r = 0; r < 4; ++r) mx[r] = fmaxf(S[0][r], S[1][r]);
#pragma unroll
        for (int d = 1; d < 16; d <<= 1) {
#pragma unroll
            for (int r = 0; r < 4; ++r) mx[r] = fmaxf(mx[r], __shfl_xor(mx[r], d));
        }

        float f[4];
#pragma unroll
        for (int r = 0; r < 4; ++r) {
            float nm = fmaxf(mrow[r], mx[r]);
            f[r] = __expf(mrow[r] - nm);   // m=-inf only before any valid key; nm finite at step 0
            mrow[r] = nm;
        }

        // ---- p = exp(S - m)
#pragma unroll
        for (int t = 0; t < 2; ++t) {
#pragma unroll
            for (int r = 0; r < 4; ++r) S[t][r] = __expf(S[t][r] - mrow[r]);
        }

        // ---- row sum + online update of l
#pragma unroll
        for (int r = 0; r < 4; ++r) {
            float rsum = S[0][r] + S[1][r];
#pragma unroll
            for (int d = 1; d < 16; d <<= 1) rsum += __shfl_xor(rsum, d);
            lrow[r] = lrow[r] * f[r] + rsum;
        }

        // ---- rescale O
#pragma unroll
        for (int ht = 0; ht < 4; ++ht) {
#pragma unroll
            for (int r = 0; r < 4; ++r) o[ht][r] *= f[r];
        }

        // ---- write P to LDS (C/D layout) and read back in A layout
        __syncthreads();
#pragma unroll
        for (int t = 0; t < 2; ++t) {
#pragma unroll
            for (int r = 0; r < 4; ++r)
                pbuf[wave][lg * 4 + r][t * 16 + lr] = (f16)S[t][r];
        }
        __syncthreads();
        f16x8 pf = *(const f16x8*)(&pbuf[wave][lr][lg * 8]);

        // ---- PV: 4 h-tiles, contraction over 32 keys
#pragma unroll
        for (int ht = 0; ht < 4; ++ht) {
            f16x8 vf = *(const f16x8*)(Vb + (size_t)(ht * 16 + lr) * NT + s0 + lg * 8);
            o[ht] = __builtin_amdgcn_mfma_f32_16x16x32_f16(pf, vf, o[ht], 0, 0, 0);
        }
        __syncthreads();
    }

    // ---- epilogue: out = o / l
    float* ob = out + (size_t)b * NT * NH;
#pragma unroll
    for (int ht = 0; ht < 4; ++ht) {
#pragma unroll
        for (int r = 0; r < 4; ++r) {
            int q = qrow + lg * 4 + r;
            ob[(size_t)q * NH + ht * 16 + lr] = o[ht][r] / lrow[r];
        }
    }
}

extern "C" void kernel_launch(void* const* d_in, const int* in_sizes, int n_in,
                              void* d_out, int out_size, void* d_ws, size_t ws_size,
                              hipStream_t stream) {
    const float* x  = (const float*)d_in[0];
    const float* Wk = (const float*)d_in[1];
    const float* Wq = (const float*)d_in[2];
    const float* Wv = (const float*)d_in[3];
    float* out = (float*)d_out;

    char* ws = (char*)d_ws;
    f16* wt = (f16*)ws;                                   // 3*64*1024*2   = 393216 B
    f16* Qh = (f16*)(ws + 393216);                        // 8*2048*64*2   = 2 MiB
    f16* Kh = (f16*)(ws + 393216 + 2097152);
    f16* VT = (f16*)(ws + 393216 + 2 * 2097152);

    hipLaunchKernelGGL(wconv_kernel, dim3(768), dim3(256), 0, stream, Wk, Wq, Wv, wt);
    hipLaunchKernelGGL(qkv_proj_kernel, dim3(128), dim3(256), 0, stream, x, wt, Qh, Kh, VT);
    hipLaunchKernelGGL(attn_kernel, dim3(256), dim3(256), 0, stream, Qh, Kh, VT, out);
}

// Round 4
// 206.134 us; speedup vs baseline: 1.3216x; 1.3216x over previous
//
#include <hip/hip_runtime.h>
#include <hip/hip_bf16.h>

typedef _Float16 f16;
typedef _Float16 f16x8 __attribute__((ext_vector_type(8)));
typedef float f32x4 __attribute__((ext_vector_type(4)));

#define NB 8
#define NT 2048
#define NE 1024
#define NH 64

#define CHUNKS_PER_BATCH 144   // sum over qi=0..31 of ceil((qi+1)/4)
#define MAXC 8                 // max chunks per q-row

// ws layout (bytes)
#define OFF_WT 0
#define OFF_QH 393216
#define OFF_KH 2490368
#define OFF_VT 4587520
#define OFF_ML 6684672          // 16384*8 float2  = 1 MiB
#define OFF_OP 7733248          // 16384*8*64 f16  = 16 MiB

// ---------------- kernel 0: weight convert + transpose -------------------
__global__ void wconv_kernel(const float* __restrict__ Wk, const float* __restrict__ Wq,
                             const float* __restrict__ Wv, f16* __restrict__ wt) {
    int idx = blockIdx.x * 256 + threadIdx.x;
    if (idx >= 3 * NH * NE) return;
    int mat = idx >> 16;
    int o = idx & 65535;
    int h = o >> 10;
    int e = o & 1023;
    const float* W = (mat == 0) ? Wq : (mat == 1) ? Wk : Wv;
    wt[idx] = (f16)W[e * NH + h];
}

// ---------------- kernel 1: fused QKV projection (MFMA f16) --------------
// x [16384][1024] fp32, wt [3][64][1024] f16 -> Qh,Kh [B*T][64], VT [B][64][T]
__global__ __launch_bounds__(256) void qkv_proj_kernel(
        const float* __restrict__ x, const f16* __restrict__ wt,
        f16* __restrict__ Qh, f16* __restrict__ Kh, f16* __restrict__ VT) {
    const int wave = threadIdx.x >> 6;
    const int lane = threadIdx.x & 63;
    const int lr = lane & 15;
    const int lg = lane >> 4;
    const int m0 = blockIdx.x * 64 + wave * 16;   // 16 rows per wave

    f32x4 acc[12] = {};   // 12 N-tiles (q:0-3, k:4-7, v:8-11)

#pragma unroll 2
    for (int kk = 0; kk < NE; kk += 32) {
        const float* px = x + (size_t)(m0 + lr) * NE + kk + lg * 8;
        float4 u0 = *(const float4*)px;
        float4 u1 = *(const float4*)(px + 4);
        f16x8 a = { (f16)u0.x, (f16)u0.y, (f16)u0.z, (f16)u0.w,
                    (f16)u1.x, (f16)u1.y, (f16)u1.z, (f16)u1.w };
#pragma unroll
        for (int nt = 0; nt < 12; ++nt) {
            const f16* pw = wt + (size_t)(nt >> 2) * (NH * NE)
                               + (size_t)((nt & 3) * 16 + lr) * NE + kk + lg * 8;
            f16x8 b = *(const f16x8*)pw;
            acc[nt] = __builtin_amdgcn_mfma_f32_16x16x32_f16(a, b, acc[nt], 0, 0, 0);
        }
    }

#pragma unroll
    for (int nt = 0; nt < 12; ++nt) {
        int mat = nt >> 2;
        int ncol = (nt & 3) * 16 + lr;
#pragma unroll
        for (int r = 0; r < 4; ++r) {
            int m = m0 + lg * 4 + r;
            f16 val = (f16)acc[nt][r];
            if (mat == 0) {
                Qh[(size_t)m * NH + ncol] = val;
            } else if (mat == 1) {
                Kh[(size_t)m * NH + ncol] = val;
            } else {
                int bb = m >> 11;
                int tt = m & 2047;
                VT[((size_t)bb * NH + ncol) * NT + tt] = val;
            }
        }
    }
}

// ---------------- kernel 2: causal flash attention, split-KV partials ----
// grid = NB * CHUNKS_PER_BATCH; each block: 64 q rows (4 waves x 16), <=8 KV steps
__global__ __launch_bounds__(256) void attn_part_kernel(
        const f16* __restrict__ Qh, const f16* __restrict__ Kh,
        const f16* __restrict__ VT, f16* __restrict__ op, float2* __restrict__ ml) {
    __shared__ f16 pbuf[4][16][40];

    const int wave = threadIdx.x >> 6;
    const int lane = threadIdx.x & 63;
    const int lr = lane & 15;
    const int lg = lane >> 4;

    const int b = blockIdx.x / CHUNKS_PER_BATCH;
    int c = blockIdx.x % CHUNKS_PER_BATCH;
    int qi = 0;
    for (; qi < 32; ++qi) {
        int ncq = (qi + 4) >> 2;
        if (c < ncq) break;
        c -= ncq;
    }
    const int total_steps = (qi + 1) * 2;       // 32-key steps in this q-block's range
    const int sbeg = c * 8;
    const int send = min(sbeg + 8, total_steps);
    const int qbase = qi * 64;
    const int qrow = qbase + wave * 16;

    const f16* Qb = Qh + (size_t)b * NT * NH;
    const f16* Kb = Kh + (size_t)b * NT * NH;
    const f16* Vb = VT + (size_t)b * NH * NT;

    f16x8 qf[2];
#pragma unroll
    for (int h = 0; h < 2; ++h)
        qf[h] = *(const f16x8*)(Qb + (size_t)(qrow + lr) * NH + h * 32 + lg * 8);

    f32x4 o[4] = {};
    float mrow[4], lrow[4];
#pragma unroll
    for (int r = 0; r < 4; ++r) { mrow[r] = -INFINITY; lrow[r] = 0.f; }

    const float scale = 0.125f;

    for (int s = sbeg; s < send; ++s) {
        const int s0 = s * 32;

        f32x4 S[2] = {};
#pragma unroll
        for (int t = 0; t < 2; ++t) {
#pragma unroll
            for (int h = 0; h < 2; ++h) {
                f16x8 kf = *(const f16x8*)(Kb + (size_t)(s0 + t * 16 + lr) * NH + h * 32 + lg * 8);
                S[t] = __builtin_amdgcn_mfma_f32_16x16x32_f16(qf[h], kf, S[t], 0, 0, 0);
            }
        }

#pragma unroll
        for (int t = 0; t < 2; ++t) {
#pragma unroll
            for (int r = 0; r < 4; ++r) {
                int q = qrow + lg * 4 + r;
                int key = s0 + t * 16 + lr;
                float sv = S[t][r] * scale;
                S[t][r] = (key <= q) ? sv : -INFINITY;
            }
        }

        float mx[4];
#pragma unroll
        for (int r = 0; r < 4; ++r) mx[r] = fmaxf(S[0][r], S[1][r]);
#pragma unroll
        for (int d = 1; d < 16; d <<= 1) {
#pragma unroll
            for (int r = 0; r < 4; ++r) mx[r] = fmaxf(mx[r], __shfl_xor(mx[r], d));
        }

        float f[4], nms[4];
#pragma unroll
        for (int r = 0; r < 4; ++r) {
            float nm = fmaxf(mrow[r], mx[r]);
            nms[r] = (nm == -INFINITY) ? 0.f : nm;   // NaN guard for fully-masked rows
            f[r] = __expf(mrow[r] - nms[r]);          // 0 when mrow == -inf
            mrow[r] = nm;
        }

#pragma unroll
        for (int t = 0; t < 2; ++t) {
#pragma unroll
            for (int r = 0; r < 4; ++r) S[t][r] = __expf(S[t][r] - nms[r]);
        }

#pragma unroll
        for (int r = 0; r < 4; ++r) {
            float rsum = S[0][r] + S[1][r];
#pragma unroll
            for (int d = 1; d < 16; d <<= 1) rsum += __shfl_xor(rsum, d);
            lrow[r] = lrow[r] * f[r] + rsum;
        }

#pragma unroll
        for (int ht = 0; ht < 4; ++ht) {
#pragma unroll
            for (int r = 0; r < 4; ++r) o[ht][r] *= f[r];
        }

        // per-wave LDS transpose (no block barrier needed: pbuf[wave] is wave-private;
        // same-wave LDS ops are ordered, compiler inserts lgkmcnt for may-alias)
#pragma unroll
        for (int t = 0; t < 2; ++t) {
#pragma unroll
            for (int r = 0; r < 4; ++r)
                pbuf[wave][lg * 4 + r][t * 16 + lr] = (f16)S[t][r];
        }
        __builtin_amdgcn_wave_barrier();
        f16x8 pf = *(const f16x8*)(&pbuf[wave][lr][lg * 8]);

#pragma unroll
        for (int ht = 0; ht < 4; ++ht) {
            f16x8 vf = *(const f16x8*)(Vb + (size_t)(ht * 16 + lr) * NT + s0 + lg * 8);
            o[ht] = __builtin_amdgcn_mfma_f32_16x16x32_f16(pf, vf, o[ht], 0, 0, 0);
        }
        __builtin_amdgcn_wave_barrier();
    }

    // ---- write partials (unnormalized o, running m/l)
#pragma unroll
    for (int r = 0; r < 4; ++r) {
        int qt = qrow + lg * 4 + r;
        size_t slot = ((size_t)b * NT + qt) * MAXC + c;
#pragma unroll
        for (int ht = 0; ht < 4; ++ht)
            op[slot * NH + ht * 16 + lr] = (f16)o[ht][r];
        if (lr == 0) {
            float2 v; v.x = mrow[r]; v.y = lrow[r];
            ml[slot] = v;
        }
    }
}

// ---------------- kernel 3: combine split-KV partials --------------------
__global__ __launch_bounds__(256) void combine_kernel(
        const f16* __restrict__ op, const float2* __restrict__ ml,
        float* __restrict__ out) {
    int gid = blockIdx.x * 256 + threadIdx.x;
    int row = gid >> 6;        // b*2048 + q
    int h = gid & 63;
    int q = row & (NT - 1);
    int qi = q >> 6;
    int nc = (qi + 4) >> 2;

    size_t base = (size_t)row * MAXC;
    float2 ml0 = ml[base];
    float M = ml0.x, L = ml0.y;
    float O = (float)op[base * NH + h];
    for (int cc = 1; cc < nc; ++cc) {
        float2 mlc = ml[base + cc];
        if (mlc.x == -INFINITY) continue;      // chunk fully masked for this row
        float oc = (float)op[(base + cc) * NH + h];
        float nM = fmaxf(M, mlc.x);
        float wo = __expf(M - nM), wc = __expf(mlc.x - nM);
        O = O * wo + oc * wc;
        L = L * wo + mlc.y * wc;
        M = nM;
    }
    out[gid] = O / L;
}

extern "C" void kernel_launch(void* const* d_in, const int* in_sizes, int n_in,
                              void* d_out, int out_size, void* d_ws, size_t ws_size,
                              hipStream_t stream) {
    const float* x  = (const float*)d_in[0];
    const float* Wk = (const float*)d_in[1];
    const float* Wq = (const float*)d_in[2];
    const float* Wv = (const float*)d_in[3];
    float* out = (float*)d_out;

    char* ws = (char*)d_ws;
    f16* wt    = (f16*)(ws + OFF_WT);
    f16* Qh    = (f16*)(ws + OFF_QH);
    f16* Kh    = (f16*)(ws + OFF_KH);
    f16* VT    = (f16*)(ws + OFF_VT);
    float2* ml = (float2*)(ws + OFF_ML);
    f16* op    = (f16*)(ws + OFF_OP);

    hipLaunchKernelGGL(wconv_kernel, dim3(768), dim3(256), 0, stream, Wk, Wq, Wv, wt);
    hipLaunchKernelGGL(qkv_proj_kernel, dim3(256), dim3(256), 0, stream, x, wt, Qh, Kh, VT);
    hipLaunchKernelGGL(attn_part_kernel, dim3(NB * CHUNKS_PER_BATCH), dim3(256), 0, stream,
                       Qh, Kh, VT, op, ml);
    hipLaunchKernelGGL(combine_kernel, dim3(NB * NT * NH / 256), dim3(256), 0, stream,
                       op, ml, out);
}